// Round 6
// baseline (3470.069 us; speedup 1.0000x reference)
//
#include <hip/hip_runtime.h>
#include <hip/hip_bf16.h>
#include <math.h>

#define LNUM 12
#define BNUM 8
#define DNUM 2048
#define VNUM 32000
#define HNUM 64
#define HDNUM 64
#define GNUM 8
#define NNUM 128
#define KNUM 4
#define INUM (HNUM*HDNUM)              /* 4096 */
#define CONVNUM (INUM + 2*GNUM*NNUM)   /* 6144 */
#define PNUM (INUM + CONVNUM + HNUM)   /* 14304 */

#define IP_KC 16                       /* in_proj row chunks (128 rows, 4 waves x 32) */
#define OP_KC 64                       /* out_proj row chunks (64 rows, 4 waves x 16) */
#define GRID 512                       /* 2 blocks/CU guaranteed resident */

struct MParams {
  const int* ids;
  const float* conv_states; const float* ssm_states;
  const float* emb; const float* norm_w; const float* in_proj_w;
  const float* conv_w; const float* conv_b; const float* dt_bias;
  const float* A_log; const float* D_param; const float* gn_w;
  const float* out_proj_w;
  float* conv_out_st; float* ssm_out_st;
  float* h; float* yg; float* ygsq; float* sqp; float* part1; float* part2;
  int* bar_cnt;
};

__device__ __forceinline__ float sigmoidf_(float x){ return 1.f/(1.f+expf(-x)); }

// Monotonic grid barrier: no counter reset -> no arrival/reset race.
// threadfence (agent scope: L2 wb/inv on gfx950) publishes data across XCDs.
__device__ __forceinline__ void gbar(int* cnt, int target){
  __syncthreads();
  if (threadIdx.x == 0){
    __threadfence();
    __hip_atomic_fetch_add(cnt, 1, __ATOMIC_RELAXED, __HIP_MEMORY_SCOPE_AGENT);
    long spins = 0;
    while (__hip_atomic_load(cnt, __ATOMIC_RELAXED, __HIP_MEMORY_SCOPE_AGENT) < target){
      __builtin_amdgcn_s_sleep(2);
      if (++spins > (1L<<22)) break;   // failsafe: wrong answer beats a hang
    }
    __threadfence();
  }
  __syncthreads();
}

__global__ __launch_bounds__(256, 2) void k_mamba(MParams P){
  const int blk = blockIdx.x, t = threadIdx.x;
  const int w = t >> 6, l = t & 63;
  __shared__ float smem[3088];   // 12.3 KB, phase-dependent layout
  int bar_no = 0;

  // ---------------- embed + sqp (32 chunks of 64 per batch) ----------------
  if (blk < BNUM){
    int b = blk;
    const float* src = P.emb + (size_t)P.ids[b]*DNUM;
    float* dst = P.h + (size_t)b*DNUM;
    float4 v0 = *(const float4*)(src + t*4);
    float4 v1 = *(const float4*)(src + 1024 + t*4);
    *(float4*)(dst + t*4) = v0;
    *(float4*)(dst + 1024 + t*4) = v1;
    float q0 = v0.x*v0.x+v0.y*v0.y+v0.z*v0.z+v0.w*v0.w;
    float q1 = v1.x*v1.x+v1.y*v1.y+v1.z*v1.z+v1.w*v1.w;
    q0 += __shfl_xor(q0,1); q0 += __shfl_xor(q0,2); q0 += __shfl_xor(q0,4); q0 += __shfl_xor(q0,8);
    q1 += __shfl_xor(q1,1); q1 += __shfl_xor(q1,2); q1 += __shfl_xor(q1,4); q1 += __shfl_xor(q1,8);
    if ((t & 15) == 0){
      P.sqp[b*32 + (t>>4)]      = q0;
      P.sqp[b*32 + 16 + (t>>4)] = q1;
    }
  }
  gbar(P.bar_cnt, GRID * (++bar_no));

  for (int li = 0; li < LNUM; ++li){
    const float* Wi   = P.in_proj_w  + (size_t)li*DNUM*PNUM;
    const float* nw   = P.norm_w     + (size_t)li*DNUM;
    const float* cw   = P.conv_w     + (size_t)li*CONVNUM*KNUM;
    const float* cb   = P.conv_b     + (size_t)li*CONVNUM;
    const float* db   = P.dt_bias    + (size_t)li*HNUM;
    const float* al   = P.A_log      + (size_t)li*HNUM;
    const float* dpp  = P.D_param    + (size_t)li*HNUM;
    const float* gw   = P.gn_w       + (size_t)li*INUM;
    const float* Wo   = P.out_proj_w + (size_t)li*INUM*DNUM;
    const float* csin = P.conv_states + (size_t)li*BNUM*CONVNUM*KNUM;
    float*       csout= P.conv_out_st + (size_t)li*BNUM*CONVNUM*KNUM;
    const float* ssin = P.ssm_states  + (size_t)li*BNUM*HNUM*HDNUM*NNUM;
    float*       ssout= P.ssm_out_st  + (size_t)li*BNUM*HNUM*HDNUM*NNUM;

    // ---------------- Phase A: in_proj GEMV (rmsnorm fused), 896 virtual blocks ----------------
    {
      float* xs   = smem;                       // 1024
      float* invs = smem + 1024;                // 8 (+pad to 1040)
      float4* red = (float4*)(smem + 1040);     // 512 float4 = 8 KB
      for (int vb = blk; vb < 896; vb += GRID){
        int pb = vb % 56, kc = vb / 56;
        if (t < 64){
          int b = t>>3, j = t&7;
          float v = P.sqp[b*32+j] + P.sqp[b*32+8+j] + P.sqp[b*32+16+j] + P.sqp[b*32+24+j];
          v += __shfl_xor(v,1); v += __shfl_xor(v,2); v += __shfl_xor(v,4);
          if (j == 0) invs[b] = rsqrtf(v*(1.f/DNUM) + 1e-5f);
        }
        __syncthreads();
        int r0 = kc*128;
        for (int i = t; i < BNUM*128; i += 256){
          int b = i>>7, dl = i&127;
          xs[i] = P.h[b*DNUM + r0 + dl] * invs[b] * nw[r0 + dl];
        }
        __syncthreads();
        int p0 = pb*256 + l*4;
        bool valid = (p0 < PNUM);
        float4 acc[BNUM];
        #pragma unroll
        for (int b = 0; b < BNUM; ++b) acc[b] = make_float4(0.f,0.f,0.f,0.f);
        if (valid){
          int rbase = w*32;
          const float* wp = Wi + (size_t)(r0 + rbase)*PNUM + p0;
          #pragma unroll 4
          for (int r = 0; r < 32; ++r){
            float4 w4 = *(const float4*)wp;
            wp += PNUM;
            #pragma unroll
            for (int b = 0; b < BNUM; ++b){
              float xvv = xs[b*128 + rbase + r];
              acc[b].x += xvv*w4.x; acc[b].y += xvv*w4.y; acc[b].z += xvv*w4.z; acc[b].w += xvv*w4.w;
            }
          }
        }
        #pragma unroll
        for (int rw = 1; rw < 4; ++rw){
          if (w == rw){
            #pragma unroll
            for (int b = 0; b < BNUM; ++b) red[b*64 + l] = acc[b];
          }
          __syncthreads();
          if (w == 0){
            #pragma unroll
            for (int b = 0; b < BNUM; ++b){
              float4 r4 = red[b*64 + l];
              acc[b].x += r4.x; acc[b].y += r4.y; acc[b].z += r4.z; acc[b].w += r4.w;
            }
          }
          __syncthreads();
        }
        if (w == 0 && valid){
          #pragma unroll
          for (int b = 0; b < BNUM; ++b)
            *(float4*)(P.part1 + (size_t)(kc*BNUM + b)*PNUM + p0) = acc[b];
        }
        __syncthreads();
      }
    }
    gbar(P.bar_cnt, GRID * (++bar_no));

    // ---------------- Phase C: fused conv+silu+dt + SSM update + gate, 512 blocks ----------------
    {
      float* xv    = smem;        // 64
      float* Bsh   = smem + 64;   // 128
      float* Csh   = smem + 192;  // 128
      float* gatel = smem + 320;  // 64
      float* scal  = smem + 384;  // 2 (dt, dA)
      float* sred  = smem + 392;  // 8
      {
        int b = blk >> 6, hh = blk & 63, g = hh >> 3;
        // pass 1: x(64) | B(128) | C first half(64)
        {
          int c, kind, n;
          if (t < 64)      { kind=0; n=t;     c = hh*HDNUM + t; }
          else if (t < 192){ kind=1; n=t-64;  c = INUM + g*NNUM + n; }
          else             { kind=2; n=t-192; c = INUM + GNUM*NNUM + g*NNUM + n; }
          int p = INUM + c;
          float v = 0.f;
          #pragma unroll
          for (int kc2 = 0; kc2 < IP_KC; ++kc2) v += P.part1[(size_t)(kc2*BNUM + b)*PNUM + p];
          size_t sid = (size_t)b*CONVNUM + c;
          float4 s4 = *(const float4*)(csin + sid*KNUM);
          float4 ns = make_float4(s4.y, s4.z, s4.w, v);
          if (kind == 0 || (hh & 7) == 0) *(float4*)(csout + sid*KNUM) = ns;
          float4 w4 = *(const float4*)(cw + (size_t)c*KNUM);
          float co = ns.x*w4.x + ns.y*w4.y + ns.z*w4.z + ns.w*w4.w + cb[c];
          float sv = co * sigmoidf_(co);
          if (kind == 0) xv[n] = sv; else if (kind == 1) Bsh[n] = sv; else Csh[n] = sv;
        }
        // pass 2: C second half(64) | gate(64) | dt(1)
        if (t < 64){
          int n = 64 + t; int c = INUM + GNUM*NNUM + g*NNUM + n; int p = INUM + c;
          float v = 0.f;
          #pragma unroll
          for (int kc2 = 0; kc2 < IP_KC; ++kc2) v += P.part1[(size_t)(kc2*BNUM + b)*PNUM + p];
          size_t sid = (size_t)b*CONVNUM + c;
          float4 s4 = *(const float4*)(csin + sid*KNUM);
          float4 ns = make_float4(s4.y, s4.z, s4.w, v);
          if ((hh & 7) == 0) *(float4*)(csout + sid*KNUM) = ns;
          float4 w4 = *(const float4*)(cw + (size_t)c*KNUM);
          float co = ns.x*w4.x + ns.y*w4.y + ns.z*w4.z + ns.w*w4.w + cb[c];
          Csh[n] = co * sigmoidf_(co);
        } else if (t < 128){
          int gc = hh*HDNUM + (t-64);
          float v = 0.f;
          #pragma unroll
          for (int kc2 = 0; kc2 < IP_KC; ++kc2) v += P.part1[(size_t)(kc2*BNUM + b)*PNUM + gc];
          gatel[t-64] = v;
        } else if (t == 128){
          int p = INUM + CONVNUM + hh;
          float v = 0.f;
          #pragma unroll
          for (int kc2 = 0; kc2 < IP_KC; ++kc2) v += P.part1[(size_t)(kc2*BNUM + b)*PNUM + p];
          float dtr = v + db[hh];
          float dt = (dtr > 20.f) ? dtr : log1pf(expf(dtr));
          dt = fminf(dt, 10000.f);
          scal[0] = dt;
          scal[1] = expf(dt * (-expf(al[hh])));
        }
        __syncthreads();
        float dt = scal[0], dA = scal[1], dp = dpp[hh];
        int r = t & 31, a2 = t >> 5;
        float4 Bv = *(float4*)&Bsh[r*4];
        float4 Cv = *(float4*)&Csh[r*4];
        const float* si = ssin  + (size_t)(b*HNUM + hh)*HDNUM*NNUM;
        float*       so = ssout + (size_t)(b*HNUM + hh)*HDNUM*NNUM;
        float s_yg = 0.f;
        #pragma unroll
        for (int k = 0; k < 8; ++k){
          int hd = k*8 + a2;
          float xvv = xv[hd];
          float coef = dt * xvv;
          int off = k*1024 + t*4;
          float4 s4 = *(const float4*)(si + off);
          float4 ns;
          ns.x = s4.x*dA + coef*Bv.x;
          ns.y = s4.y*dA + coef*Bv.y;
          ns.z = s4.z*dA + coef*Bv.z;
          ns.w = s4.w*dA + coef*Bv.w;
          *(float4*)(so + off) = ns;
          float yp = ns.x*Cv.x + ns.y*Cv.y + ns.z*Cv.z + ns.w*Cv.w;
          yp += __shfl_xor(yp,1); yp += __shfl_xor(yp,2); yp += __shfl_xor(yp,4);
          yp += __shfl_xor(yp,8); yp += __shfl_xor(yp,16);
          if (r == 0){
            float gv = gatel[hd];
            float ygv = (yp + xvv*dp) * gv * sigmoidf_(gv);
            P.yg[b*INUM + hh*HDNUM + hd] = ygv;
            s_yg += ygv*ygv;
          }
        }
        if (r == 0) sred[a2] = s_yg;
        __syncthreads();
        if (t == 0){
          float tot = 0.f;
          #pragma unroll
          for (int j = 0; j < 8; ++j) tot += sred[j];
          P.ygsq[b*HNUM + hh] = tot;
        }
      }
    }
    gbar(P.bar_cnt, GRID * (++bar_no));

    // ---------------- Phase D: out_proj GEMV (gated rmsnorm fused), 512 blocks ----------------
    {
      float* xs   = smem;                    // 512
      float* invg = smem + 512;              // 8 (+pad to 520)
      float4* red = (float4*)(smem + 520);   // 512 float4 = 8 KB
      {
        int pb = blk & 7, kc = blk >> 3;
        if (t < 64){
          int b = t>>3, j = t&7;
          float v = 0.f;
          #pragma unroll
          for (int jj = 0; jj < 8; ++jj) v += P.ygsq[b*HNUM + j + jj*8];
          v += __shfl_xor(v,1); v += __shfl_xor(v,2); v += __shfl_xor(v,4);
          if (j == 0) invg[b] = rsqrtf(v*(1.f/INUM) + 1e-5f);
        }
        __syncthreads();
        int r0 = kc*64;
        for (int i = t; i < BNUM*64; i += 256){
          int b = i>>6, il = i&63;
          xs[i] = P.yg[b*INUM + r0 + il] * invg[b] * gw[r0 + il];
        }
        __syncthreads();
        int d0 = pb*256 + l*4;
        float4 acc[BNUM];
        #pragma unroll
        for (int b = 0; b < BNUM; ++b) acc[b] = make_float4(0.f,0.f,0.f,0.f);
        {
          int rbase = w*16;
          const float* wp = Wo + (size_t)(r0 + rbase)*DNUM + d0;
          #pragma unroll 4
          for (int r2 = 0; r2 < 16; ++r2){
            float4 w4 = *(const float4*)wp;
            wp += DNUM;
            #pragma unroll
            for (int b = 0; b < BNUM; ++b){
              float xvv = xs[b*64 + rbase + r2];
              acc[b].x += xvv*w4.x; acc[b].y += xvv*w4.y; acc[b].z += xvv*w4.z; acc[b].w += xvv*w4.w;
            }
          }
        }
        #pragma unroll
        for (int rw = 1; rw < 4; ++rw){
          if (w == rw){
            #pragma unroll
            for (int b = 0; b < BNUM; ++b) red[b*64 + l] = acc[b];
          }
          __syncthreads();
          if (w == 0){
            #pragma unroll
            for (int b = 0; b < BNUM; ++b){
              float4 r4 = red[b*64 + l];
              acc[b].x += r4.x; acc[b].y += r4.y; acc[b].z += r4.z; acc[b].w += r4.w;
            }
          }
          __syncthreads();
        }
        if (w == 0){
          #pragma unroll
          for (int b = 0; b < BNUM; ++b)
            *(float4*)(P.part2 + (size_t)(kc*BNUM + b)*DNUM + d0) = acc[b];
        }
      }
    }
    gbar(P.bar_cnt, GRID * (++bar_no));

    // ---------------- Phase E: reduce + residual + sqp, 64 blocks ----------------
    {
      if (blk < 64){
        int idx = blk*256 + t;   // < B*D = 16384
        float s = P.h[idx];
        #pragma unroll 8
        for (int ic = 0; ic < OP_KC; ++ic) s += P.part2[(size_t)ic*BNUM*DNUM + idx];
        P.h[idx] = s;
        float q = s*s;
        q += __shfl_xor(q,32); q += __shfl_xor(q,16); q += __shfl_xor(q,8);
        q += __shfl_xor(q,4);  q += __shfl_xor(q,2);  q += __shfl_xor(q,1);
        if (l == 0) P.sqp[idx>>6] = q;   // chunk = b*32 + d/64
      }
    }
    gbar(P.bar_cnt, GRID * (++bar_no));
  }
}

// ---------------- lm_head (final rmsnorm fused), separate launch ----------------
__global__ __launch_bounds__(256) void k_lmhead(const float* __restrict__ h,
                                                const float* __restrict__ sqp,
                                                const float* __restrict__ nf,
                                                const float* __restrict__ Wl,
                                                float* __restrict__ logits){
  __shared__ float hs[BNUM*DNUM];   // 64KB
  __shared__ float invb_s[8];
  int t = threadIdx.x;
  if (t < 8){
    float s = 0.f;
    #pragma unroll
    for (int j = 0; j < 32; ++j) s += sqp[t*32 + j];
    invb_s[t] = rsqrtf(s*(1.f/DNUM) + 1e-5f);
  }
  __syncthreads();
  #pragma unroll
  for (int it = 0; it < 16; ++it){
    int i = t*4 + it*1024;
    float iv = invb_s[it>>1];
    float4 hv  = *(const float4*)(h + i);
    float4 nfv = *(const float4*)(nf + (i & 2047));
    float4 o;
    o.x = hv.x*iv*nfv.x; o.y = hv.y*iv*nfv.y; o.z = hv.z*iv*nfv.z; o.w = hv.w*iv*nfv.w;
    *(float4*)(hs + i) = o;
  }
  __syncthreads();
  int wv = t >> 6, lane = t & 63;
  int v0 = (blockIdx.x*4 + wv)*4;
  float acc[4][BNUM];
  #pragma unroll
  for (int u = 0; u < 4; ++u)
    #pragma unroll
    for (int b = 0; b < BNUM; ++b) acc[u][b] = 0.f;
  #pragma unroll
  for (int j = 0; j < 8; ++j){
    int dbase = j*256 + lane*4;
    float4 w0 = *(const float4*)(Wl + (size_t)(v0+0)*DNUM + dbase);
    float4 w1 = *(const float4*)(Wl + (size_t)(v0+1)*DNUM + dbase);
    float4 w2 = *(const float4*)(Wl + (size_t)(v0+2)*DNUM + dbase);
    float4 w3 = *(const float4*)(Wl + (size_t)(v0+3)*DNUM + dbase);
    #pragma unroll
    for (int b = 0; b < BNUM; ++b){
      float4 hv = *(const float4*)(hs + b*DNUM + dbase);
      acc[0][b] += w0.x*hv.x + w0.y*hv.y + w0.z*hv.z + w0.w*hv.w;
      acc[1][b] += w1.x*hv.x + w1.y*hv.y + w1.z*hv.z + w1.w*hv.w;
      acc[2][b] += w2.x*hv.x + w2.y*hv.y + w2.z*hv.z + w2.w*hv.w;
      acc[3][b] += w3.x*hv.x + w3.y*hv.y + w3.z*hv.z + w3.w*hv.w;
    }
  }
  #pragma unroll
  for (int u = 0; u < 4; ++u)
    #pragma unroll
    for (int b = 0; b < BNUM; ++b){
      float s = acc[u][b];
      s += __shfl_xor(s,32); s += __shfl_xor(s,16); s += __shfl_xor(s,8);
      s += __shfl_xor(s,4);  s += __shfl_xor(s,2);  s += __shfl_xor(s,1);
      if (lane == 0) logits[(size_t)b*VNUM + v0 + u] = s;
    }
}

extern "C" void kernel_launch(void* const* d_in, const int* in_sizes, int n_in,
                              void* d_out, int out_size, void* d_ws, size_t ws_size,
                              hipStream_t stream){
  const int*   ids         = (const int*)d_in[0];
  const float* conv_states = (const float*)d_in[1];
  const float* ssm_states  = (const float*)d_in[2];
  const float* emb         = (const float*)d_in[3];
  const float* norm_w      = (const float*)d_in[4];
  const float* in_proj_w   = (const float*)d_in[5];
  const float* conv_w      = (const float*)d_in[6];
  const float* conv_b      = (const float*)d_in[7];
  const float* dt_bias     = (const float*)d_in[8];
  const float* A_log       = (const float*)d_in[9];
  const float* D_param     = (const float*)d_in[10];
  const float* gn_w        = (const float*)d_in[11];
  const float* out_proj_w  = (const float*)d_in[12];
  const float* norm_f_w    = (const float*)d_in[13];
  const float* lm_head_w   = (const float*)d_in[14];

  float* out         = (float*)d_out;
  float* logits      = out;
  float* conv_out_st = out + (size_t)BNUM*VNUM;
  float* ssm_out_st  = conv_out_st + (size_t)LNUM*BNUM*CONVNUM*KNUM;

  float* ws    = (float*)d_ws;
  float* h     = ws;                   // B*D   = 16384
  float* yg    = h    + 16384;         // B*I   = 32768
  float* ygsq  = yg   + 32768;         // B*H   = 512
  float* sqp   = ygsq + 512;           // B*32  = 256
  float* part1 = sqp  + 256;           // 16*B*P = 1830912
  float* part2 = part1+ 1830912;       // 64*B*D = 1048576
  int*   bar   = (int*)(part2 + 1048576);

  hipMemsetAsync(bar, 0, 128, stream);

  MParams P;
  P.ids = ids; P.conv_states = conv_states; P.ssm_states = ssm_states;
  P.emb = emb; P.norm_w = norm_w; P.in_proj_w = in_proj_w;
  P.conv_w = conv_w; P.conv_b = conv_b; P.dt_bias = dt_bias;
  P.A_log = A_log; P.D_param = D_param; P.gn_w = gn_w;
  P.out_proj_w = out_proj_w;
  P.conv_out_st = conv_out_st; P.ssm_out_st = ssm_out_st;
  P.h = h; P.yg = yg; P.ygsq = ygsq; P.sqp = sqp; P.part1 = part1; P.part2 = part2;
  P.bar_cnt = bar;

  k_mamba<<<GRID, 256, 0, stream>>>(P);
  k_lmhead<<<VNUM/16, 256, 0, stream>>>(h, sqp, norm_f_w, lm_head_w, logits);
}

// Round 7
// 1382.934 us; speedup vs baseline: 2.5092x; 2.5092x over previous
//
#include <hip/hip_runtime.h>
#include <hip/hip_bf16.h>
#include <math.h>

#define LNUM 12
#define BNUM 8
#define DNUM 2048
#define VNUM 32000
#define HNUM 64
#define HDNUM 64
#define GNUM 8
#define NNUM 128
#define KNUM 4
#define INUM (HNUM*HDNUM)              /* 4096 */
#define CONVNUM (INUM + 2*GNUM*NNUM)   /* 6144 */
#define PNUM (INUM + CONVNUM + HNUM)   /* 14304 */

#define IP_KC 16                       /* in_proj row chunks (128 rows, 4 waves x 32) */
#define OP_KC 64                       /* out_proj row chunks (64 rows, 4 waves x 16) */
#define GRID 512                       /* 2 blocks/CU guaranteed resident */

struct MParams {
  const int* ids;
  const float* conv_states; const float* ssm_states;
  const float* emb; const float* norm_w; const float* in_proj_w;
  const float* conv_w; const float* conv_b; const float* dt_bias;
  const float* A_log; const float* D_param; const float* gn_w;
  const float* out_proj_w;
  float* conv_out_st; float* ssm_out_st;
  float* h; float* yg; float* ygsq; float* sqp; float* part1; float* part2;
  int* arrive;   // 512 slots, stride 16 ints (64B padded)
  int* release;  // 1 flag
};

__device__ __forceinline__ float sigmoidf_(float x){ return 1.f/(1.f+expf(-x)); }

// Agent-scope (device-coherent, MALL-direct) scalar accesses — bypass per-XCD L2.
__device__ __forceinline__ int   uc_load_i (const int* p){ return __hip_atomic_load((int*)p, __ATOMIC_RELAXED, __HIP_MEMORY_SCOPE_AGENT); }
__device__ __forceinline__ void  uc_store_i(int* p, int v){ __hip_atomic_store(p, v, __ATOMIC_RELAXED, __HIP_MEMORY_SCOPE_AGENT); }
__device__ __forceinline__ float uc_load_f (const float* p){ return __hip_atomic_load((float*)p, __ATOMIC_RELAXED, __HIP_MEMORY_SCOPE_AGENT); }
__device__ __forceinline__ void  uc_store_f(float* p, float v){ __hip_atomic_store(p, v, __ATOMIC_RELAXED, __HIP_MEMORY_SCOPE_AGENT); }

// Two-level broadcast barrier: per-block arrival slots (no RMW contention),
// master (block 0) scans slots in parallel, single release-flag store.
// No threadfence: all cross-block data moves via agent-scope (MALL) ops, and
// __syncthreads + per-wave vmcnt drain orders data ahead of the flag.
__device__ __forceinline__ void gbar(const MParams& P, int epoch){
  __syncthreads();   // hipcc drains vmcnt/lgkmcnt for every wave before s_barrier
  if (blockIdx.x == 0){
    for (int i = 1 + threadIdx.x; i < GRID; i += 256){
      long spins = 0;
      while (uc_load_i(&P.arrive[i*16]) < epoch){
        __builtin_amdgcn_s_sleep(1);
        if (++spins > (1L<<22)) break;   // failsafe: wrong answer beats a hang
      }
    }
    __syncthreads();
    if (threadIdx.x == 0){
      asm volatile("s_waitcnt vmcnt(0) lgkmcnt(0)" ::: "memory");
      uc_store_i(P.release, epoch);
    }
  } else {
    if (threadIdx.x == 0){
      asm volatile("s_waitcnt vmcnt(0) lgkmcnt(0)" ::: "memory");
      uc_store_i(&P.arrive[blockIdx.x*16], epoch);
      long spins = 0;
      while (uc_load_i(P.release) < epoch){
        __builtin_amdgcn_s_sleep(1);
        if (++spins > (1L<<22)) break;
      }
    }
    __syncthreads();
  }
  asm volatile("" ::: "memory");
}

__global__ __launch_bounds__(256, 2) void k_mamba(MParams P){
  const int blk = blockIdx.x, t = threadIdx.x;
  const int w = t >> 6, l = t & 63;
  __shared__ float smem[3088];   // 12.3 KB, phase-dependent layout
  int bar_no = 0;

  // ---------------- embed + sqp (32 chunks of 64 per batch) ----------------
  if (blk < BNUM){
    int b = blk;
    const float* src = P.emb + (size_t)P.ids[b]*DNUM;
    float* dst = P.h + (size_t)b*DNUM;
    float4 v0 = *(const float4*)(src + t*4);
    float4 v1 = *(const float4*)(src + 1024 + t*4);
    uc_store_f(dst + t*4 + 0, v0.x); uc_store_f(dst + t*4 + 1, v0.y);
    uc_store_f(dst + t*4 + 2, v0.z); uc_store_f(dst + t*4 + 3, v0.w);
    uc_store_f(dst + 1024 + t*4 + 0, v1.x); uc_store_f(dst + 1024 + t*4 + 1, v1.y);
    uc_store_f(dst + 1024 + t*4 + 2, v1.z); uc_store_f(dst + 1024 + t*4 + 3, v1.w);
    float q0 = v0.x*v0.x+v0.y*v0.y+v0.z*v0.z+v0.w*v0.w;
    float q1 = v1.x*v1.x+v1.y*v1.y+v1.z*v1.z+v1.w*v1.w;
    q0 += __shfl_xor(q0,1); q0 += __shfl_xor(q0,2); q0 += __shfl_xor(q0,4); q0 += __shfl_xor(q0,8);
    q1 += __shfl_xor(q1,1); q1 += __shfl_xor(q1,2); q1 += __shfl_xor(q1,4); q1 += __shfl_xor(q1,8);
    if ((t & 15) == 0){
      uc_store_f(&P.sqp[b*32 + (t>>4)],      q0);
      uc_store_f(&P.sqp[b*32 + 16 + (t>>4)], q1);
    }
  }
  gbar(P, ++bar_no);

  for (int li = 0; li < LNUM; ++li){
    const float* Wi   = P.in_proj_w  + (size_t)li*DNUM*PNUM;
    const float* nw   = P.norm_w     + (size_t)li*DNUM;
    const float* cw   = P.conv_w     + (size_t)li*CONVNUM*KNUM;
    const float* cb   = P.conv_b     + (size_t)li*CONVNUM;
    const float* db   = P.dt_bias    + (size_t)li*HNUM;
    const float* al   = P.A_log      + (size_t)li*HNUM;
    const float* dpp  = P.D_param    + (size_t)li*HNUM;
    const float* gw   = P.gn_w       + (size_t)li*INUM;
    const float* Wo   = P.out_proj_w + (size_t)li*INUM*DNUM;
    const float* csin = P.conv_states + (size_t)li*BNUM*CONVNUM*KNUM;
    float*       csout= P.conv_out_st + (size_t)li*BNUM*CONVNUM*KNUM;
    const float* ssin = P.ssm_states  + (size_t)li*BNUM*HNUM*HDNUM*NNUM;
    float*       ssout= P.ssm_out_st  + (size_t)li*BNUM*HNUM*HDNUM*NNUM;

    // ---------------- Phase A: in_proj GEMV (rmsnorm fused), 896 virtual blocks ----------------
    {
      float* xs   = smem;                       // 1024
      float* invs = smem + 1024;                // 8 (+pad to 1040)
      float4* red = (float4*)(smem + 1040);     // 512 float4 = 8 KB
      for (int vb = blk; vb < 896; vb += GRID){
        int pb = vb % 56, kc = vb / 56;
        if (t < 64){
          int b = t>>3, j = t&7;
          float v = uc_load_f(&P.sqp[b*32+j]) + uc_load_f(&P.sqp[b*32+8+j])
                  + uc_load_f(&P.sqp[b*32+16+j]) + uc_load_f(&P.sqp[b*32+24+j]);
          v += __shfl_xor(v,1); v += __shfl_xor(v,2); v += __shfl_xor(v,4);
          if (j == 0) invs[b] = rsqrtf(v*(1.f/DNUM) + 1e-5f);
        }
        __syncthreads();
        int r0 = kc*128;
        for (int i = t; i < BNUM*128; i += 256){
          int b = i>>7, dl = i&127;
          xs[i] = uc_load_f(&P.h[b*DNUM + r0 + dl]) * invs[b] * nw[r0 + dl];
        }
        __syncthreads();
        int p0 = pb*256 + l*4;
        bool valid = (p0 < PNUM);
        float4 acc[BNUM];
        #pragma unroll
        for (int b = 0; b < BNUM; ++b) acc[b] = make_float4(0.f,0.f,0.f,0.f);
        if (valid){
          int rbase = w*32;
          const float* wp = Wi + (size_t)(r0 + rbase)*PNUM + p0;
          #pragma unroll 4
          for (int r = 0; r < 32; ++r){
            float4 w4 = *(const float4*)wp;
            wp += PNUM;
            #pragma unroll
            for (int b = 0; b < BNUM; ++b){
              float xvv = xs[b*128 + rbase + r];
              acc[b].x += xvv*w4.x; acc[b].y += xvv*w4.y; acc[b].z += xvv*w4.z; acc[b].w += xvv*w4.w;
            }
          }
        }
        #pragma unroll
        for (int rw = 1; rw < 4; ++rw){
          if (w == rw){
            #pragma unroll
            for (int b = 0; b < BNUM; ++b) red[b*64 + l] = acc[b];
          }
          __syncthreads();
          if (w == 0){
            #pragma unroll
            for (int b = 0; b < BNUM; ++b){
              float4 r4 = red[b*64 + l];
              acc[b].x += r4.x; acc[b].y += r4.y; acc[b].z += r4.z; acc[b].w += r4.w;
            }
          }
          __syncthreads();
        }
        if (w == 0 && valid){
          #pragma unroll
          for (int b = 0; b < BNUM; ++b){
            float* dst = P.part1 + (size_t)(kc*BNUM + b)*PNUM + p0;
            uc_store_f(dst+0, acc[b].x); uc_store_f(dst+1, acc[b].y);
            uc_store_f(dst+2, acc[b].z); uc_store_f(dst+3, acc[b].w);
          }
        }
        __syncthreads();
      }
    }
    gbar(P, ++bar_no);

    // ---------------- Phase C: fused conv+silu+dt + SSM update + gate, 512 blocks ----------------
    {
      float* xv    = smem;        // 64
      float* Bsh   = smem + 64;   // 128
      float* Csh   = smem + 192;  // 128
      float* gatel = smem + 320;  // 64
      float* scal  = smem + 384;  // 2 (dt, dA)
      float* sred  = smem + 392;  // 8
      {
        int b = blk >> 6, hh = blk & 63, g = hh >> 3;
        // pass 1: x(64) | B(128) | C first half(64)
        {
          int c, kind, n;
          if (t < 64)      { kind=0; n=t;     c = hh*HDNUM + t; }
          else if (t < 192){ kind=1; n=t-64;  c = INUM + g*NNUM + n; }
          else             { kind=2; n=t-192; c = INUM + GNUM*NNUM + g*NNUM + n; }
          int p = INUM + c;
          float v = 0.f;
          #pragma unroll
          for (int kc2 = 0; kc2 < IP_KC; ++kc2) v += uc_load_f(&P.part1[(size_t)(kc2*BNUM + b)*PNUM + p]);
          size_t sid = (size_t)b*CONVNUM + c;
          float4 s4 = *(const float4*)(csin + sid*KNUM);
          float4 ns = make_float4(s4.y, s4.z, s4.w, v);
          if (kind == 0 || (hh & 7) == 0) *(float4*)(csout + sid*KNUM) = ns;
          float4 w4 = *(const float4*)(cw + (size_t)c*KNUM);
          float co = ns.x*w4.x + ns.y*w4.y + ns.z*w4.z + ns.w*w4.w + cb[c];
          float sv = co * sigmoidf_(co);
          if (kind == 0) xv[n] = sv; else if (kind == 1) Bsh[n] = sv; else Csh[n] = sv;
        }
        // pass 2: C second half(64) | gate(64) | dt(1)
        if (t < 64){
          int n = 64 + t; int c = INUM + GNUM*NNUM + g*NNUM + n; int p = INUM + c;
          float v = 0.f;
          #pragma unroll
          for (int kc2 = 0; kc2 < IP_KC; ++kc2) v += uc_load_f(&P.part1[(size_t)(kc2*BNUM + b)*PNUM + p]);
          size_t sid = (size_t)b*CONVNUM + c;
          float4 s4 = *(const float4*)(csin + sid*KNUM);
          float4 ns = make_float4(s4.y, s4.z, s4.w, v);
          if ((hh & 7) == 0) *(float4*)(csout + sid*KNUM) = ns;
          float4 w4 = *(const float4*)(cw + (size_t)c*KNUM);
          float co = ns.x*w4.x + ns.y*w4.y + ns.z*w4.z + ns.w*w4.w + cb[c];
          Csh[n] = co * sigmoidf_(co);
        } else if (t < 128){
          int gc = hh*HDNUM + (t-64);
          float v = 0.f;
          #pragma unroll
          for (int kc2 = 0; kc2 < IP_KC; ++kc2) v += uc_load_f(&P.part1[(size_t)(kc2*BNUM + b)*PNUM + gc]);
          gatel[t-64] = v;
        } else if (t == 128){
          int p = INUM + CONVNUM + hh;
          float v = 0.f;
          #pragma unroll
          for (int kc2 = 0; kc2 < IP_KC; ++kc2) v += uc_load_f(&P.part1[(size_t)(kc2*BNUM + b)*PNUM + p]);
          float dtr = v + db[hh];
          float dt = (dtr > 20.f) ? dtr : log1pf(expf(dtr));
          dt = fminf(dt, 10000.f);
          scal[0] = dt;
          scal[1] = expf(dt * (-expf(al[hh])));
        }
        __syncthreads();
        float dt = scal[0], dA = scal[1], dp = dpp[hh];
        int r = t & 31, a2 = t >> 5;
        float4 Bv = *(float4*)&Bsh[r*4];
        float4 Cv = *(float4*)&Csh[r*4];
        const float* si = ssin  + (size_t)(b*HNUM + hh)*HDNUM*NNUM;
        float*       so = ssout + (size_t)(b*HNUM + hh)*HDNUM*NNUM;
        float s_yg = 0.f;
        #pragma unroll
        for (int k = 0; k < 8; ++k){
          int hd = k*8 + a2;
          float xvv = xv[hd];
          float coef = dt * xvv;
          int off = k*1024 + t*4;
          float4 s4 = *(const float4*)(si + off);
          float4 ns;
          ns.x = s4.x*dA + coef*Bv.x;
          ns.y = s4.y*dA + coef*Bv.y;
          ns.z = s4.z*dA + coef*Bv.z;
          ns.w = s4.w*dA + coef*Bv.w;
          *(float4*)(so + off) = ns;
          float yp = ns.x*Cv.x + ns.y*Cv.y + ns.z*Cv.z + ns.w*Cv.w;
          yp += __shfl_xor(yp,1); yp += __shfl_xor(yp,2); yp += __shfl_xor(yp,4);
          yp += __shfl_xor(yp,8); yp += __shfl_xor(yp,16);
          if (r == 0){
            float gv = gatel[hd];
            float ygv = (yp + xvv*dp) * gv * sigmoidf_(gv);
            uc_store_f(&P.yg[b*INUM + hh*HDNUM + hd], ygv);
            s_yg += ygv*ygv;
          }
        }
        if (r == 0) sred[a2] = s_yg;
        __syncthreads();
        if (t == 0){
          float tot = 0.f;
          #pragma unroll
          for (int j = 0; j < 8; ++j) tot += sred[j];
          uc_store_f(&P.ygsq[b*HNUM + hh], tot);
        }
      }
    }
    gbar(P, ++bar_no);

    // ---------------- Phase D: out_proj GEMV (gated rmsnorm fused), 512 blocks ----------------
    {
      float* xs   = smem;                    // 512
      float* invg = smem + 512;              // 8 (+pad to 520)
      float4* red = (float4*)(smem + 520);   // 512 float4 = 8 KB
      {
        int pb = blk & 7, kc = blk >> 3;
        if (t < 64){
          int b = t>>3, j = t&7;
          float v = 0.f;
          #pragma unroll
          for (int jj = 0; jj < 8; ++jj) v += uc_load_f(&P.ygsq[b*HNUM + j + jj*8]);
          v += __shfl_xor(v,1); v += __shfl_xor(v,2); v += __shfl_xor(v,4);
          if (j == 0) invg[b] = rsqrtf(v*(1.f/INUM) + 1e-5f);
        }
        __syncthreads();
        int r0 = kc*64;
        for (int i = t; i < BNUM*64; i += 256){
          int b = i>>6, il = i&63;
          xs[i] = uc_load_f(&P.yg[b*INUM + r0 + il]) * invg[b] * gw[r0 + il];
        }
        __syncthreads();
        int d0 = pb*256 + l*4;
        float4 acc[BNUM];
        #pragma unroll
        for (int b = 0; b < BNUM; ++b) acc[b] = make_float4(0.f,0.f,0.f,0.f);
        {
          int rbase = w*16;
          const float* wp = Wo + (size_t)(r0 + rbase)*DNUM + d0;
          #pragma unroll 4
          for (int r2 = 0; r2 < 16; ++r2){
            float4 w4 = *(const float4*)wp;
            wp += DNUM;
            #pragma unroll
            for (int b = 0; b < BNUM; ++b){
              float xvv = xs[b*64 + rbase + r2];
              acc[b].x += xvv*w4.x; acc[b].y += xvv*w4.y; acc[b].z += xvv*w4.z; acc[b].w += xvv*w4.w;
            }
          }
        }
        #pragma unroll
        for (int rw = 1; rw < 4; ++rw){
          if (w == rw){
            #pragma unroll
            for (int b = 0; b < BNUM; ++b) red[b*64 + l] = acc[b];
          }
          __syncthreads();
          if (w == 0){
            #pragma unroll
            for (int b = 0; b < BNUM; ++b){
              float4 r4 = red[b*64 + l];
              acc[b].x += r4.x; acc[b].y += r4.y; acc[b].z += r4.z; acc[b].w += r4.w;
            }
          }
          __syncthreads();
        }
        if (w == 0){
          #pragma unroll
          for (int b = 0; b < BNUM; ++b){
            float* dst = P.part2 + (size_t)(kc*BNUM + b)*DNUM + d0;
            uc_store_f(dst+0, acc[b].x); uc_store_f(dst+1, acc[b].y);
            uc_store_f(dst+2, acc[b].z); uc_store_f(dst+3, acc[b].w);
          }
        }
      }
    }
    gbar(P, ++bar_no);

    // ---------------- Phase E: reduce + residual + sqp, 64 blocks ----------------
    {
      if (blk < 64){
        int idx = blk*256 + t;   // < B*D = 16384
        float s = uc_load_f(&P.h[idx]);
        #pragma unroll 8
        for (int ic = 0; ic < OP_KC; ++ic) s += uc_load_f(&P.part2[(size_t)ic*BNUM*DNUM + idx]);
        uc_store_f(&P.h[idx], s);
        float q = s*s;
        q += __shfl_xor(q,32); q += __shfl_xor(q,16); q += __shfl_xor(q,8);
        q += __shfl_xor(q,4);  q += __shfl_xor(q,2);  q += __shfl_xor(q,1);
        if (l == 0) uc_store_f(&P.sqp[idx>>6], q);   // chunk = b*32 + d/64
      }
    }
    gbar(P, ++bar_no);
  }
}

// ---------------- lm_head (final rmsnorm fused), separate launch ----------------
__global__ __launch_bounds__(256) void k_lmhead(const float* __restrict__ h,
                                                const float* __restrict__ sqp,
                                                const float* __restrict__ nf,
                                                const float* __restrict__ Wl,
                                                float* __restrict__ logits){
  __shared__ float hs[BNUM*DNUM];   // 64KB
  __shared__ float invb_s[8];
  int t = threadIdx.x;
  if (t < 8){
    float s = 0.f;
    #pragma unroll
    for (int j = 0; j < 32; ++j) s += sqp[t*32 + j];
    invb_s[t] = rsqrtf(s*(1.f/DNUM) + 1e-5f);
  }
  __syncthreads();
  #pragma unroll
  for (int it = 0; it < 16; ++it){
    int i = t*4 + it*1024;
    float iv = invb_s[it>>1];
    float4 hv  = *(const float4*)(h + i);
    float4 nfv = *(const float4*)(nf + (i & 2047));
    float4 o;
    o.x = hv.x*iv*nfv.x; o.y = hv.y*iv*nfv.y; o.z = hv.z*iv*nfv.z; o.w = hv.w*iv*nfv.w;
    *(float4*)(hs + i) = o;
  }
  __syncthreads();
  int wv = t >> 6, lane = t & 63;
  int v0 = (blockIdx.x*4 + wv)*4;
  float acc[4][BNUM];
  #pragma unroll
  for (int u = 0; u < 4; ++u)
    #pragma unroll
    for (int b = 0; b < BNUM; ++b) acc[u][b] = 0.f;
  #pragma unroll
  for (int j = 0; j < 8; ++j){
    int dbase = j*256 + lane*4;
    float4 w0 = *(const float4*)(Wl + (size_t)(v0+0)*DNUM + dbase);
    float4 w1 = *(const float4*)(Wl + (size_t)(v0+1)*DNUM + dbase);
    float4 w2 = *(const float4*)(Wl + (size_t)(v0+2)*DNUM + dbase);
    float4 w3 = *(const float4*)(Wl + (size_t)(v0+3)*DNUM + dbase);
    #pragma unroll
    for (int b = 0; b < BNUM; ++b){
      float4 hv = *(const float4*)(hs + b*DNUM + dbase);
      acc[0][b] += w0.x*hv.x + w0.y*hv.y + w0.z*hv.z + w0.w*hv.w;
      acc[1][b] += w1.x*hv.x + w1.y*hv.y + w1.z*hv.z + w1.w*hv.w;
      acc[2][b] += w2.x*hv.x + w2.y*hv.y + w2.z*hv.z + w2.w*hv.w;
      acc[3][b] += w3.x*hv.x + w3.y*hv.y + w3.z*hv.z + w3.w*hv.w;
    }
  }
  #pragma unroll
  for (int u = 0; u < 4; ++u)
    #pragma unroll
    for (int b = 0; b < BNUM; ++b){
      float s = acc[u][b];
      s += __shfl_xor(s,32); s += __shfl_xor(s,16); s += __shfl_xor(s,8);
      s += __shfl_xor(s,4);  s += __shfl_xor(s,2);  s += __shfl_xor(s,1);
      if (lane == 0) logits[(size_t)b*VNUM + v0 + u] = s;
    }
}

extern "C" void kernel_launch(void* const* d_in, const int* in_sizes, int n_in,
                              void* d_out, int out_size, void* d_ws, size_t ws_size,
                              hipStream_t stream){
  const int*   ids         = (const int*)d_in[0];
  const float* conv_states = (const float*)d_in[1];
  const float* ssm_states  = (const float*)d_in[2];
  const float* emb         = (const float*)d_in[3];
  const float* norm_w      = (const float*)d_in[4];
  const float* in_proj_w   = (const float*)d_in[5];
  const float* conv_w      = (const float*)d_in[6];
  const float* conv_b      = (const float*)d_in[7];
  const float* dt_bias     = (const float*)d_in[8];
  const float* A_log       = (const float*)d_in[9];
  const float* D_param     = (const float*)d_in[10];
  const float* gn_w        = (const float*)d_in[11];
  const float* out_proj_w  = (const float*)d_in[12];
  const float* norm_f_w    = (const float*)d_in[13];
  const float* lm_head_w   = (const float*)d_in[14];

  float* out         = (float*)d_out;
  float* logits      = out;
  float* conv_out_st = out + (size_t)BNUM*VNUM;
  float* ssm_out_st  = conv_out_st + (size_t)LNUM*BNUM*CONVNUM*KNUM;

  float* ws    = (float*)d_ws;
  float* h     = ws;                   // B*D   = 16384
  float* yg    = h    + 16384;         // B*I   = 32768
  float* ygsq  = yg   + 32768;         // B*H   = 512
  float* sqp   = ygsq + 512;           // B*32  = 256
  float* part1 = sqp  + 256;           // 16*B*P = 1830912
  float* part2 = part1+ 1830912;       // 64*B*D = 1048576
  int*   bar   = (int*)(part2 + 1048576);  // 512*16 + 16 ints

  hipMemsetAsync(bar, 0, (GRID*16 + 16)*sizeof(int), stream);

  MParams P;
  P.ids = ids; P.conv_states = conv_states; P.ssm_states = ssm_states;
  P.emb = emb; P.norm_w = norm_w; P.in_proj_w = in_proj_w;
  P.conv_w = conv_w; P.conv_b = conv_b; P.dt_bias = dt_bias;
  P.A_log = A_log; P.D_param = D_param; P.gn_w = gn_w;
  P.out_proj_w = out_proj_w;
  P.conv_out_st = conv_out_st; P.ssm_out_st = ssm_out_st;
  P.h = h; P.yg = yg; P.ygsq = ygsq; P.sqp = sqp; P.part1 = part1; P.part2 = part2;
  P.arrive = bar; P.release = bar + GRID*16;

  k_mamba<<<GRID, 256, 0, stream>>>(P);
  k_lmhead<<<VNUM/16, 256, 0, stream>>>(h, sqp, norm_f_w, lm_head_w, logits);
}

// Round 8
// 1155.205 us; speedup vs baseline: 3.0039x; 1.1971x over previous
//
#include <hip/hip_runtime.h>
#include <hip/hip_bf16.h>
#include <math.h>

#define LNUM 12
#define BNUM 8
#define DNUM 2048
#define VNUM 32000
#define HNUM 64
#define HDNUM 64
#define GNUM 8
#define NNUM 128
#define KNUM 4
#define INUM (HNUM*HDNUM)              /* 4096 */
#define CONVNUM (INUM + 2*GNUM*NNUM)   /* 6144 */
#define PNUM (INUM + CONVNUM + HNUM)   /* 14304 */

#define IP_KC 16                       /* in_proj row chunks (128 rows) */
#define GRID 1024                      /* 4 blocks/CU resident by construction */

struct MParams {
  const int* ids;
  const float* conv_states; const float* ssm_states;
  const float* emb; const float* norm_w; const float* in_proj_w;
  const float* conv_w; const float* conv_b; const float* dt_bias;
  const float* A_log; const float* D_param; const float* gn_w;
  const float* out_proj_w;
  float* conv_out_st; float* ssm_out_st;
  float* h; float* yg; float* ygsq; float* sqp; float* part1;
  int* arrive;   // GRID slots, stride 16 ints
  int* release;  // 1 flag
};

__device__ __forceinline__ float sigmoidf_(float x){ return 1.f/(1.f+expf(-x)); }

// Agent-scope (MALL-direct) accesses — bypass non-coherent per-XCD L2.
__device__ __forceinline__ int   uc_load_i (const int* p){ return __hip_atomic_load((int*)p, __ATOMIC_RELAXED, __HIP_MEMORY_SCOPE_AGENT); }
__device__ __forceinline__ void  uc_store_i(int* p, int v){ __hip_atomic_store(p, v, __ATOMIC_RELAXED, __HIP_MEMORY_SCOPE_AGENT); }
__device__ __forceinline__ float uc_load_f (const float* p){ return __hip_atomic_load((float*)p, __ATOMIC_RELAXED, __HIP_MEMORY_SCOPE_AGENT); }
__device__ __forceinline__ void  uc_store_f(float* p, float v){ __hip_atomic_store(p, v, __ATOMIC_RELAXED, __HIP_MEMORY_SCOPE_AGENT); }
__device__ __forceinline__ void  uc_add_f  (float* p, float v){ __hip_atomic_fetch_add(p, v, __ATOMIC_RELAXED, __HIP_MEMORY_SCOPE_AGENT); }

// Two-level broadcast barrier (validated R7): per-block arrival slots, master
// scan, single release flag. Data ordered by per-wave vmcnt drain + MALL path.
__device__ __forceinline__ void gbar(const MParams& P, int epoch){
  __syncthreads();
  if (blockIdx.x == 0){
    for (int i = 1 + threadIdx.x; i < GRID; i += 256){
      long spins = 0;
      while (uc_load_i(&P.arrive[i*16]) < epoch){
        __builtin_amdgcn_s_sleep(1);
        if (++spins > (1L<<22)) break;   // failsafe: wrong answer beats a hang
      }
    }
    __syncthreads();
    if (threadIdx.x == 0){
      asm volatile("s_waitcnt vmcnt(0) lgkmcnt(0)" ::: "memory");
      uc_store_i(P.release, epoch);
    }
  } else {
    if (threadIdx.x == 0){
      asm volatile("s_waitcnt vmcnt(0) lgkmcnt(0)" ::: "memory");
      uc_store_i(&P.arrive[blockIdx.x*16], epoch);
      long spins = 0;
      while (uc_load_i(P.release) < epoch){
        __builtin_amdgcn_s_sleep(1);
        if (++spins > (1L<<22)) break;
      }
    }
    __syncthreads();
  }
  asm volatile("" ::: "memory");
}

__global__ __launch_bounds__(256, 4) void k_mamba(MParams P){
  const int blk = blockIdx.x, t = threadIdx.x;
  const int w = t >> 6, l = t & 63;
  __shared__ float smem[3088];   // 12.35 KB, phase-dependent layout
  int bar_no = 0;

  // ---------------- embed + full-row sqp ----------------
  if (blk < BNUM){
    int b = blk;
    const float* src = P.emb + (size_t)P.ids[b]*DNUM;
    float* dst = P.h + (size_t)b*DNUM;
    float4 v0 = *(const float4*)(src + t*4);
    float4 v1 = *(const float4*)(src + 1024 + t*4);
    uc_store_f(dst + t*4 + 0, v0.x); uc_store_f(dst + t*4 + 1, v0.y);
    uc_store_f(dst + t*4 + 2, v0.z); uc_store_f(dst + t*4 + 3, v0.w);
    uc_store_f(dst + 1024 + t*4 + 0, v1.x); uc_store_f(dst + 1024 + t*4 + 1, v1.y);
    uc_store_f(dst + 1024 + t*4 + 2, v1.z); uc_store_f(dst + 1024 + t*4 + 3, v1.w);
    float q = v0.x*v0.x+v0.y*v0.y+v0.z*v0.z+v0.w*v0.w
            + v1.x*v1.x+v1.y*v1.y+v1.z*v1.z+v1.w*v1.w;
    q += __shfl_xor(q,32); q += __shfl_xor(q,16); q += __shfl_xor(q,8);
    q += __shfl_xor(q,4);  q += __shfl_xor(q,2);  q += __shfl_xor(q,1);
    if (l == 0) smem[w] = q;
    __syncthreads();
    if (t == 0) uc_store_f(&P.sqp[b], smem[0]+smem[1]+smem[2]+smem[3]);
  }
  gbar(P, ++bar_no);

  for (int li = 0; li < LNUM; ++li){
    const float* Wi   = P.in_proj_w  + (size_t)li*DNUM*PNUM;
    const float* nw   = P.norm_w     + (size_t)li*DNUM;
    const float* cw   = P.conv_w     + (size_t)li*CONVNUM*KNUM;
    const float* cb   = P.conv_b     + (size_t)li*CONVNUM;
    const float* db   = P.dt_bias    + (size_t)li*HNUM;
    const float* al   = P.A_log      + (size_t)li*HNUM;
    const float* dpp  = P.D_param    + (size_t)li*HNUM;
    const float* gw   = P.gn_w       + (size_t)li*INUM;
    const float* Wo   = P.out_proj_w + (size_t)li*INUM*DNUM;
    const float* csin = P.conv_states + (size_t)li*BNUM*CONVNUM*KNUM;
    float*       csout= P.conv_out_st + (size_t)li*BNUM*CONVNUM*KNUM;
    const float* ssin = P.ssm_states  + (size_t)li*BNUM*HNUM*HDNUM*NNUM;
    float*       ssout= P.ssm_out_st  + (size_t)li*BNUM*HNUM*HDNUM*NNUM;

    // ---- Phase A: in_proj GEMV, UNNORMALIZED (inv deferred to C). 896 tiles
    //      + 8 blocks compute sqp of current h. 1 tile per block (balanced). ----
    {
      float*  xs  = smem;                    // 1024
      float4* red = (float4*)(smem + 1024);  // 512 float4
      if (blk < 896){
        int pb = blk % 56, kc = blk / 56;
        int r0 = kc*128;
        for (int i = t; i < BNUM*128; i += 256){
          int b = i>>7, dl = i&127;
          xs[i] = uc_load_f(&P.h[b*DNUM + r0 + dl]) * nw[r0 + dl];
        }
        __syncthreads();
        int p0 = pb*256 + l*4;
        bool valid = (p0 < PNUM);
        float4 acc[BNUM];
        #pragma unroll
        for (int b = 0; b < BNUM; ++b) acc[b] = make_float4(0.f,0.f,0.f,0.f);
        if (valid){
          int rbase = w*32;
          const float* wp = Wi + (size_t)(r0 + rbase)*PNUM + p0;
          #pragma unroll 4
          for (int r = 0; r < 32; ++r){
            float4 w4 = *(const float4*)wp;
            wp += PNUM;
            #pragma unroll
            for (int b = 0; b < BNUM; ++b){
              float xvv = xs[b*128 + rbase + r];
              acc[b].x += xvv*w4.x; acc[b].y += xvv*w4.y; acc[b].z += xvv*w4.z; acc[b].w += xvv*w4.w;
            }
          }
        }
        #pragma unroll
        for (int rw = 1; rw < 4; ++rw){
          if (w == rw){
            #pragma unroll
            for (int b = 0; b < BNUM; ++b) red[b*64 + l] = acc[b];
          }
          __syncthreads();
          if (w == 0){
            #pragma unroll
            for (int b = 0; b < BNUM; ++b){
              float4 r4 = red[b*64 + l];
              acc[b].x += r4.x; acc[b].y += r4.y; acc[b].z += r4.z; acc[b].w += r4.w;
            }
          }
          __syncthreads();
        }
        if (w == 0){
          #pragma unroll
          for (int b = 0; b < BNUM; ++b) red[b*64 + l] = acc[b];
        }
        __syncthreads();
        // coalesced dword stores: redf[b*256 + c] = col c of strip
        const float* redf = (const float*)red;
        if (pb*256 + t < PNUM){
          #pragma unroll
          for (int b = 0; b < BNUM; ++b)
            uc_store_f(&P.part1[(size_t)(kc*BNUM + b)*PNUM + pb*256 + t], redf[b*256 + t]);
        }
      } else if (blk < 896 + BNUM){
        int b = blk - 896;
        float q = 0.f;
        for (int i = t; i < DNUM; i += 256){
          float v = uc_load_f(&P.h[b*DNUM + i]);
          q += v*v;
        }
        q += __shfl_xor(q,32); q += __shfl_xor(q,16); q += __shfl_xor(q,8);
        q += __shfl_xor(q,4);  q += __shfl_xor(q,2);  q += __shfl_xor(q,1);
        if (l == 0) smem[w] = q;
        __syncthreads();
        if (t == 0) uc_store_f(&P.sqp[b], smem[0]+smem[1]+smem[2]+smem[3]);
      }
    }
    gbar(P, ++bar_no);

    // ---- Phase C: reduce part1 (×inv) + conv/silu/dt + SSM + gate.
    //      1024 blocks = 8 b × 64 heads × 2 half-heads (32 hd each). ----
    {
      float* xv    = smem;        // 32
      float* gatel = smem + 32;   // 32
      float* Bsh   = smem + 64;   // 128
      float* Csh   = smem + 192;  // 128
      float* scal  = smem + 320;  // [0]=dt [1]=dA [2]=inv
      float* sred  = smem + 328;  // 8
      int b = blk >> 7, rest = blk & 127, hh = rest >> 1, half = rest & 1, g = hh >> 3;
      if (t == 0) scal[2] = rsqrtf(uc_load_f(&P.sqp[b]) * (1.f/DNUM) + 1e-5f);
      __syncthreads();
      float inv = scal[2];
      // pass 1: B (t<128) | C (t>=128)
      {
        int n = t & 127;
        int c = (t < 128) ? (INUM + g*NNUM + n) : (INUM + GNUM*NNUM + g*NNUM + n);
        int p = INUM + c;
        float v = 0.f;
        #pragma unroll
        for (int kc2 = 0; kc2 < IP_KC; ++kc2) v += uc_load_f(&P.part1[(size_t)(kc2*BNUM + b)*PNUM + p]);
        v *= inv;
        size_t sid = (size_t)b*CONVNUM + c;
        float4 s4 = *(const float4*)(csin + sid*KNUM);
        float4 ns = make_float4(s4.y, s4.z, s4.w, v);
        if ((hh & 7) == 0 && half == 0) *(float4*)(csout + sid*KNUM) = ns;
        float4 w4 = *(const float4*)(cw + (size_t)c*KNUM);
        float co = ns.x*w4.x + ns.y*w4.y + ns.z*w4.z + ns.w*w4.w + cb[c];
        float sv = co * sigmoidf_(co);
        if (t < 128) Bsh[n] = sv; else Csh[n] = sv;
      }
      // pass 2: x(32) | gate(32) | dt(1)
      if (t < 32){
        int hd = half*32 + t;
        int c = hh*HDNUM + hd;
        int p = INUM + c;
        float v = 0.f;
        #pragma unroll
        for (int kc2 = 0; kc2 < IP_KC; ++kc2) v += uc_load_f(&P.part1[(size_t)(kc2*BNUM + b)*PNUM + p]);
        v *= inv;
        size_t sid = (size_t)b*CONVNUM + c;
        float4 s4 = *(const float4*)(csin + sid*KNUM);
        float4 ns = make_float4(s4.y, s4.z, s4.w, v);
        *(float4*)(csout + sid*KNUM) = ns;
        float4 w4 = *(const float4*)(cw + (size_t)c*KNUM);
        float co = ns.x*w4.x + ns.y*w4.y + ns.z*w4.z + ns.w*w4.w + cb[c];
        xv[t] = co * sigmoidf_(co);
      } else if (t < 64){
        int hd = half*32 + (t-32);
        int p = hh*HDNUM + hd;
        float v = 0.f;
        #pragma unroll
        for (int kc2 = 0; kc2 < IP_KC; ++kc2) v += uc_load_f(&P.part1[(size_t)(kc2*BNUM + b)*PNUM + p]);
        gatel[t-32] = v * inv;
      } else if (t == 64){
        int p = INUM + CONVNUM + hh;
        float v = 0.f;
        #pragma unroll
        for (int kc2 = 0; kc2 < IP_KC; ++kc2) v += uc_load_f(&P.part1[(size_t)(kc2*BNUM + b)*PNUM + p]);
        float dtr = v*inv + db[hh];
        float dt = (dtr > 20.f) ? dtr : log1pf(expf(dtr));
        dt = fminf(dt, 10000.f);
        scal[0] = dt;
        scal[1] = expf(dt * (-expf(al[hh])));
      }
      __syncthreads();
      float dt = scal[0], dA = scal[1], dp = dpp[hh];
      int r = t & 31, a2 = t >> 5;
      float4 Bv = *(float4*)&Bsh[r*4];
      float4 Cv = *(float4*)&Csh[r*4];
      const float* si = ssin  + (size_t)(b*HNUM + hh)*HDNUM*NNUM + half*4096;
      float*       so = ssout + (size_t)(b*HNUM + hh)*HDNUM*NNUM + half*4096;
      float s_yg = 0.f;
      #pragma unroll
      for (int k = 0; k < 4; ++k){
        int hdl = k*8 + a2;            // 0..31 within half
        float xvv = xv[hdl];
        float coef = dt * xvv;
        int off = k*1024 + t*4;
        float4 s4 = *(const float4*)(si + off);
        float4 ns;
        ns.x = s4.x*dA + coef*Bv.x;
        ns.y = s4.y*dA + coef*Bv.y;
        ns.z = s4.z*dA + coef*Bv.z;
        ns.w = s4.w*dA + coef*Bv.w;
        *(float4*)(so + off) = ns;
        float yp = ns.x*Cv.x + ns.y*Cv.y + ns.z*Cv.z + ns.w*Cv.w;
        yp += __shfl_xor(yp,1); yp += __shfl_xor(yp,2); yp += __shfl_xor(yp,4);
        yp += __shfl_xor(yp,8); yp += __shfl_xor(yp,16);
        if (r == 0){
          float gv = gatel[hdl];
          float ygv = (yp + xvv*dp) * gv * sigmoidf_(gv);
          uc_store_f(&P.yg[b*INUM + hh*HDNUM + half*32 + hdl], ygv);
          s_yg += ygv*ygv;
        }
      }
      if (r == 0) sred[a2] = s_yg;
      __syncthreads();
      if (t == 0){
        float tot = 0.f;
        #pragma unroll
        for (int j = 0; j < 8; ++j) tot += sred[j];
        uc_store_f(&P.ygsq[b*128 + hh*2 + half], tot);
      }
    }
    gbar(P, ++bar_no);

    // ---- Phase D: out_proj GEMV (gated norm fused), atomicAdd into h.
    //      1024 blocks = 16 col-strips (128) × 64 row-chunks (64). ----
    {
      float*  xs   = smem;                     // 512
      float*  invg = smem + 512;               // 8 (+pad)
      float2* red2 = (float2*)(smem + 528);    // 512 float2
      int pb = blk & 15, kc = blk >> 4;
      if (t < 64){
        int b2 = t>>3, j = t&7;
        float v = 0.f;
        #pragma unroll
        for (int jj = 0; jj < 16; ++jj) v += uc_load_f(&P.ygsq[b2*128 + j + jj*8]);
        v += __shfl_xor(v,1); v += __shfl_xor(v,2); v += __shfl_xor(v,4);
        if (j == 0) invg[b2] = rsqrtf(v*(1.f/INUM) + 1e-5f);
      }
      __syncthreads();
      int r0 = kc*64;
      for (int i = t; i < BNUM*64; i += 256){
        int b = i>>6, il = i&63;
        xs[i] = uc_load_f(&P.yg[b*INUM + r0 + il]) * invg[b] * gw[r0 + il];
      }
      __syncthreads();
      int c0 = pb*128 + l*2;
      float2 acc[BNUM];
      #pragma unroll
      for (int b = 0; b < BNUM; ++b) acc[b] = make_float2(0.f,0.f);
      {
        int rbase = w*16;
        const float* wp = Wo + (size_t)(r0 + rbase)*DNUM + c0;
        #pragma unroll 4
        for (int r2 = 0; r2 < 16; ++r2){
          float2 w2 = *(const float2*)wp;
          wp += DNUM;
          #pragma unroll
          for (int b = 0; b < BNUM; ++b){
            float xvv = xs[b*64 + rbase + r2];
            acc[b].x += xvv*w2.x; acc[b].y += xvv*w2.y;
          }
        }
      }
      #pragma unroll
      for (int rw = 1; rw < 4; ++rw){
        if (w == rw){
          #pragma unroll
          for (int b = 0; b < BNUM; ++b) red2[b*64 + l] = acc[b];
        }
        __syncthreads();
        if (w == 0){
          #pragma unroll
          for (int b = 0; b < BNUM; ++b){
            float2 r2v = red2[b*64 + l];
            acc[b].x += r2v.x; acc[b].y += r2v.y;
          }
        }
        __syncthreads();
      }
      if (w == 0){
        #pragma unroll
        for (int b = 0; b < BNUM; ++b) red2[b*64 + l] = acc[b];
      }
      __syncthreads();
      const float* redf = (const float*)red2;   // redf[b*128 + cc]
      #pragma unroll
      for (int bb = 0; bb < 4; ++bb){
        int b = bb*2 + (t>>7);
        int cc = t & 127;
        uc_add_f(&P.h[b*DNUM + pb*128 + cc], redf[b*128 + cc]);
      }
    }
    gbar(P, ++bar_no);
  }

  // final sqp for lm_head (h final after last D barrier)
  if (blk >= 896 && blk < 896 + BNUM){
    int b = blk - 896;
    float q = 0.f;
    for (int i = t; i < DNUM; i += 256){
      float v = uc_load_f(&P.h[b*DNUM + i]);
      q += v*v;
    }
    q += __shfl_xor(q,32); q += __shfl_xor(q,16); q += __shfl_xor(q,8);
    q += __shfl_xor(q,4);  q += __shfl_xor(q,2);  q += __shfl_xor(q,1);
    if (l == 0) smem[w] = q;
    __syncthreads();
    if (t == 0) uc_store_f(&P.sqp[b], smem[0]+smem[1]+smem[2]+smem[3]);
  }
}

// ---------------- lm_head (final rmsnorm fused), separate launch ----------------
__global__ __launch_bounds__(256) void k_lmhead(const float* __restrict__ h,
                                                const float* __restrict__ sqp,
                                                const float* __restrict__ nf,
                                                const float* __restrict__ Wl,
                                                float* __restrict__ logits){
  __shared__ float hs[BNUM*DNUM];   // 64KB
  __shared__ float invb_s[8];
  int t = threadIdx.x;
  if (t < 8) invb_s[t] = rsqrtf(sqp[t]*(1.f/DNUM) + 1e-5f);
  __syncthreads();
  #pragma unroll
  for (int it = 0; it < 16; ++it){
    int i = t*4 + it*1024;
    float iv = invb_s[it>>1];
    float4 hv  = *(const float4*)(h + i);
    float4 nfv = *(const float4*)(nf + (i & 2047));
    float4 o;
    o.x = hv.x*iv*nfv.x; o.y = hv.y*iv*nfv.y; o.z = hv.z*iv*nfv.z; o.w = hv.w*iv*nfv.w;
    *(float4*)(hs + i) = o;
  }
  __syncthreads();
  int wv = t >> 6, lane = t & 63;
  int v0 = (blockIdx.x*4 + wv)*4;
  float acc[4][BNUM];
  #pragma unroll
  for (int u = 0; u < 4; ++u)
    #pragma unroll
    for (int b = 0; b < BNUM; ++b) acc[u][b] = 0.f;
  #pragma unroll
  for (int j = 0; j < 8; ++j){
    int dbase = j*256 + lane*4;
    float4 w0 = *(const float4*)(Wl + (size_t)(v0+0)*DNUM + dbase);
    float4 w1 = *(const float4*)(Wl + (size_t)(v0+1)*DNUM + dbase);
    float4 w2 = *(const float4*)(Wl + (size_t)(v0+2)*DNUM + dbase);
    float4 w3 = *(const float4*)(Wl + (size_t)(v0+3)*DNUM + dbase);
    #pragma unroll
    for (int b = 0; b < BNUM; ++b){
      float4 hv = *(const float4*)(hs + b*DNUM + dbase);
      acc[0][b] += w0.x*hv.x + w0.y*hv.y + w0.z*hv.z + w0.w*hv.w;
      acc[1][b] += w1.x*hv.x + w1.y*hv.y + w1.z*hv.z + w1.w*hv.w;
      acc[2][b] += w2.x*hv.x + w2.y*hv.y + w2.z*hv.z + w2.w*hv.w;
      acc[3][b] += w3.x*hv.x + w3.y*hv.y + w3.z*hv.z + w3.w*hv.w;
    }
  }
  #pragma unroll
  for (int u = 0; u < 4; ++u)
    #pragma unroll
    for (int b = 0; b < BNUM; ++b){
      float s = acc[u][b];
      s += __shfl_xor(s,32); s += __shfl_xor(s,16); s += __shfl_xor(s,8);
      s += __shfl_xor(s,4);  s += __shfl_xor(s,2);  s += __shfl_xor(s,1);
      if (lane == 0) logits[(size_t)b*VNUM + v0 + u] = s;
    }
}

extern "C" void kernel_launch(void* const* d_in, const int* in_sizes, int n_in,
                              void* d_out, int out_size, void* d_ws, size_t ws_size,
                              hipStream_t stream){
  const int*   ids         = (const int*)d_in[0];
  const float* conv_states = (const float*)d_in[1];
  const float* ssm_states  = (const float*)d_in[2];
  const float* emb         = (const float*)d_in[3];
  const float* norm_w      = (const float*)d_in[4];
  const float* in_proj_w   = (const float*)d_in[5];
  const float* conv_w      = (const float*)d_in[6];
  const float* conv_b      = (const float*)d_in[7];
  const float* dt_bias     = (const float*)d_in[8];
  const float* A_log       = (const float*)d_in[9];
  const float* D_param     = (const float*)d_in[10];
  const float* gn_w        = (const float*)d_in[11];
  const float* out_proj_w  = (const float*)d_in[12];
  const float* norm_f_w    = (const float*)d_in[13];
  const float* lm_head_w   = (const float*)d_in[14];

  float* out         = (float*)d_out;
  float* logits      = out;
  float* conv_out_st = out + (size_t)BNUM*VNUM;
  float* ssm_out_st  = conv_out_st + (size_t)LNUM*BNUM*CONVNUM*KNUM;

  float* ws    = (float*)d_ws;
  float* h     = ws;                   // B*D    = 16384
  float* yg    = h    + 16384;         // B*I    = 32768
  float* ygsq  = yg   + 32768;         // B*128  = 1024
  float* sqp   = ygsq + 1024;          // B (pad 64)
  float* part1 = sqp  + 64;            // 16*B*P = 1830912
  int*   bar   = (int*)(part1 + 1830912);  // GRID*16 + 16 ints

  hipMemsetAsync(bar, 0, (GRID*16 + 16)*sizeof(int), stream);

  MParams P;
  P.ids = ids; P.conv_states = conv_states; P.ssm_states = ssm_states;
  P.emb = emb; P.norm_w = norm_w; P.in_proj_w = in_proj_w;
  P.conv_w = conv_w; P.conv_b = conv_b; P.dt_bias = dt_bias;
  P.A_log = A_log; P.D_param = D_param; P.gn_w = gn_w;
  P.out_proj_w = out_proj_w;
  P.conv_out_st = conv_out_st; P.ssm_out_st = ssm_out_st;
  P.h = h; P.yg = yg; P.ygsq = ygsq; P.sqp = sqp; P.part1 = part1;
  P.arrive = bar; P.release = bar + GRID*16;

  k_mamba<<<GRID, 256, 0, stream>>>(P);
  k_lmhead<<<VNUM/16, 256, 0, stream>>>(h, sqp, norm_f_w, lm_head_w, logits);
}